// Round 1
// baseline (5373.002 us; speedup 1.0000x reference)
//
#include <hip/hip_runtime.h>
#include <cstdint>
#include <cstddef>

// ---------------------------------------------------------------------------
// FluxSingleStreamBlock on MI355X (gfx950), bf16 MFMA pipeline.
// ws layout (bytes):
//   [0,36864)                 mod (9216 f32): shift|scale|gate
//   A1  : 4608 x 3136 bf16    [x_mod | t1 | 0]
//   Bw  : 21504 x 3136 bf16   [w1 | lu1 | 0]   (later overlaid by 3072x15424 [w2|lu2|0])
//   qkv : 4608 x 6144 bf16    raw q,k from GEMM1
//   qp  : 24 x 4608 x 128 bf16  q after rms+rope, head-major
//   kp  : same for k
//   vt  : 24 x 128 x 4608 bf16  v transposed (written by GEMM1 epilogue)
//   A2  : 4608 x 15424 bf16   [attn | gelu(mlp) | t2 | 0]
// total ~447.5 MB
// ---------------------------------------------------------------------------

#define HIDC 3072
#define NHEAD 24
#define HDIM 128
#define SEQ 4608
#define D1 21504     // 3*HID + MLP
#define K1P 3136     // 3072 + 64 pad (t1/lu1 + zeros)
#define K2DIM 15360  // HID + MLP
#define K2P 15424    // + 64 pad (t2/lu2 + zeros)

typedef __bf16 bf16_t;
typedef __bf16 bf16x2 __attribute__((ext_vector_type(2)));
typedef __bf16 bf16x4 __attribute__((ext_vector_type(4)));
typedef __bf16 bf16x8 __attribute__((ext_vector_type(8)));
typedef float f32x4 __attribute__((ext_vector_type(4)));

__device__ __forceinline__ void gl_lds16(const bf16_t* g, bf16_t* l) {
  __builtin_amdgcn_global_load_lds((__attribute__((address_space(1))) void*)(g),
                                   (__attribute__((address_space(3))) void*)(l),
                                   16, 0, 0);
}

__device__ __forceinline__ float gelu_tanh(float v) {
  float c = v + 0.044715f * v * v * v;
  return 0.5f * v * (1.f + tanhf(0.7978845608028654f * c));
}

// ---------------------------------------------------------------------------
// mod = silu(vec) @ mod_w^T + mod_b   (9216 outputs, one wave each)
__global__ __launch_bounds__(256) void k_mod(const float* __restrict__ vec,
                                             const float* __restrict__ mw,
                                             const float* __restrict__ mb,
                                             float* __restrict__ mod) {
  const int lane = threadIdx.x & 63, wid = threadIdx.x >> 6;
  const int j = blockIdx.x * 4 + wid;
  const float* wr = mw + (size_t)j * HIDC;
  float s = 0.f;
  for (int i = lane * 4; i < HIDC; i += 256) {
    float4 w4 = *(const float4*)(wr + i);
    float4 v4 = *(const float4*)(vec + i);
    float a0 = v4.x / (1.f + __expf(-v4.x));
    float a1 = v4.y / (1.f + __expf(-v4.y));
    float a2 = v4.z / (1.f + __expf(-v4.z));
    float a3 = v4.w / (1.f + __expf(-v4.w));
    s += a0 * w4.x + a1 * w4.y + a2 * w4.z + a3 * w4.w;
  }
#pragma unroll
  for (int o = 32; o; o >>= 1) s += __shfl_down(s, o);
  if (lane == 0) mod[j] = s + mb[j];
}

// ---------------------------------------------------------------------------
// LayerNorm + modulation -> A1 (bf16), one block per token row
__global__ __launch_bounds__(256) void k_ln(const float* __restrict__ x,
                                            const float* __restrict__ mod,
                                            bf16_t* __restrict__ A1) {
  const int row = blockIdx.x;
  const int tid = threadIdx.x;
  const float* xr = x + (size_t)row * HIDC;
  float4 v[3];
  float s = 0.f, s2 = 0.f;
#pragma unroll
  for (int it = 0; it < 3; ++it) {
    v[it] = *(const float4*)(xr + (tid + 256 * it) * 4);
    s += v[it].x + v[it].y + v[it].z + v[it].w;
    s2 += v[it].x * v[it].x + v[it].y * v[it].y + v[it].z * v[it].z + v[it].w * v[it].w;
  }
  __shared__ float rbuf[8];
#pragma unroll
  for (int o = 32; o; o >>= 1) { s += __shfl_down(s, o); s2 += __shfl_down(s2, o); }
  const int lane = tid & 63, wid = tid >> 6;
  if (lane == 0) { rbuf[wid] = s; rbuf[4 + wid] = s2; }
  __syncthreads();
  s = rbuf[0] + rbuf[1] + rbuf[2] + rbuf[3];
  s2 = rbuf[4] + rbuf[5] + rbuf[6] + rbuf[7];
  const float mean = s * (1.f / HIDC);
  const float var = s2 * (1.f / HIDC) - mean * mean;
  const float rstd = rsqrtf(var + 1e-6f);
  bf16_t* arow = A1 + (size_t)row * K1P;
#pragma unroll
  for (int it = 0; it < 3; ++it) {
    const int c = (tid + 256 * it) * 4;
    float4 sc = *(const float4*)(mod + HIDC + c);  // scale
    float4 sh = *(const float4*)(mod + c);         // shift
    float y0 = ((v[it].x - mean) * rstd) * (1.f + sc.x) + sh.x;
    float y1 = ((v[it].y - mean) * rstd) * (1.f + sc.y) + sh.y;
    float y2 = ((v[it].z - mean) * rstd) * (1.f + sc.z) + sh.z;
    float y3 = ((v[it].w - mean) * rstd) * (1.f + sc.w) + sh.w;
    bf16x4 o = {(bf16_t)y0, (bf16_t)y1, (bf16_t)y2, (bf16_t)y3};
    *(bf16x4*)(arow + c) = o;
  }
}

// ---------------------------------------------------------------------------
// low-rank projection into A pad columns: A[row, Kmain+r] = sum_c A[row,c]*ld[r,c]
// 8 rows per block, 32 ranks; also zeroes pad cols [Kmain+32, Kmain+64)
__global__ __launch_bounds__(256) void k_lowrank(const bf16_t* __restrict__ Abuf,
                                                 const float* __restrict__ ld,
                                                 bf16_t* __restrict__ Awr,
                                                 int Kmain, int Kpad) {
  const int r = threadIdx.x & 31, slot = threadIdx.x >> 5;
  const int row = blockIdx.x * 8 + slot;
  const bf16_t* a = Abuf + (size_t)row * Kpad;
  const float* lr = ld + (size_t)r * Kmain;
  float s = 0.f;
  for (int c = 0; c < Kmain; c += 8) {
    bf16x8 av = *(const bf16x8*)(a + c);
    float4 l0 = *(const float4*)(lr + c);
    float4 l1 = *(const float4*)(lr + c + 4);
    s += (float)av[0] * l0.x + (float)av[1] * l0.y + (float)av[2] * l0.z + (float)av[3] * l0.w;
    s += (float)av[4] * l1.x + (float)av[5] * l1.y + (float)av[6] * l1.z + (float)av[7] * l1.w;
  }
  bf16_t* w = Awr + (size_t)row * Kpad + Kmain;
  w[r] = (bf16_t)s;
  w[32 + r] = (bf16_t)0.f;
}

// ---------------------------------------------------------------------------
// Pack [w | lu | 0] row to bf16, one block per output row
__global__ __launch_bounds__(256) void k_convB(const float* __restrict__ w,
                                               const float* __restrict__ lu,
                                               bf16_t* __restrict__ B,
                                               int Kmain, int Kpad) {
  const int row = blockIdx.x;
  const float* wr = w + (size_t)row * Kmain;
  const float* lr = lu + (size_t)row * 32;
  bf16_t* br = B + (size_t)row * Kpad;
  for (int c = threadIdx.x * 4; c < Kpad; c += 1024) {
    float4 v;
    if (c < Kmain) v = *(const float4*)(wr + c);
    else if (c < Kmain + 32) v = *(const float4*)(lr + (c - Kmain));
    else v = make_float4(0.f, 0.f, 0.f, 0.f);
    bf16x4 o = {(bf16_t)v.x, (bf16_t)v.y, (bf16_t)v.z, (bf16_t)v.w};
    *(bf16x4*)(br + c) = o;
  }
}

// ---------------------------------------------------------------------------
// 128x128 tile GEMM core, C = A @ B^T, A:(M x K) row-major, B:(N x K) row-major.
// LDS layout [kchunk(8)][row(128)][8 bf16] -> conflict-minimal ds_read_b128.
__device__ __forceinline__ void gemm_core(const bf16_t* __restrict__ A,
                                          const bf16_t* __restrict__ B,
                                          const int K, const int tileM, const int tileN,
                                          bf16_t* As, bf16_t* Bs, f32x4 acc[4][4]) {
  const int tid = threadIdx.x, lane = tid & 63;
  const int wid = tid >> 6, wr = wid >> 1, wc = wid & 1;
  const int quad = lane >> 4, m16 = lane & 15;
  const f32x4 fzero = {0.f, 0.f, 0.f, 0.f};
#pragma unroll
  for (int i = 0; i < 4; ++i)
#pragma unroll
    for (int j = 0; j < 4; ++j) acc[i][j] = fzero;
  const bf16_t* Ag = A + (size_t)tileM * K;
  const bf16_t* Bg = B + (size_t)tileN * K;
  for (int kt = 0; kt < K; kt += 64) {
    __syncthreads();
#pragma unroll
    for (int s = 0; s < 4; ++s) {
      int o = s * 256 + tid;
      gl_lds16(Ag + (size_t)(o & 127) * K + (size_t)(kt + (o >> 7) * 8), As + (size_t)o * 8);
    }
#pragma unroll
    for (int s = 0; s < 4; ++s) {
      int o = s * 256 + tid;
      gl_lds16(Bg + (size_t)(o & 127) * K + (size_t)(kt + (o >> 7) * 8), Bs + (size_t)o * 8);
    }
    __syncthreads();
#pragma unroll
    for (int kk = 0; kk < 2; ++kk) {
      bf16x8 af[4], bfr[4];
#pragma unroll
      for (int i = 0; i < 4; ++i)
        af[i] = *(const bf16x8*)(As + (size_t)((kk * 4 + quad) * 128 + wr * 64 + i * 16 + m16) * 8);
#pragma unroll
      for (int j = 0; j < 4; ++j)
        bfr[j] = *(const bf16x8*)(Bs + (size_t)((kk * 4 + quad) * 128 + wc * 64 + j * 16 + m16) * 8);
#pragma unroll
      for (int i = 0; i < 4; ++i)
#pragma unroll
        for (int j = 0; j < 4; ++j)
          acc[i][j] = __builtin_amdgcn_mfma_f32_16x16x32_bf16(af[i], bfr[j], acc[i][j], 0, 0, 0);
    }
  }
}

// GEMM1: A1(4608x3136) @ B1(21504x3136)^T + b1. Epilogue split:
//   col<6144: q,k -> qkv ; 6144..9215: v -> vt transposed ; >=9216: gelu -> A2
__global__ __launch_bounds__(256, 2) void k_gemm1(const bf16_t* __restrict__ A1,
                                                  const bf16_t* __restrict__ B1,
                                                  const float* __restrict__ b1,
                                                  bf16_t* __restrict__ qkv,
                                                  bf16_t* __restrict__ vt,
                                                  bf16_t* __restrict__ A2) {
  __shared__ __align__(16) bf16_t As[8192];
  __shared__ __align__(16) bf16_t Bs[8192];
  f32x4 acc[4][4];
  const int tileM = (blockIdx.x % 36) * 128, tileN = (blockIdx.x / 36) * 128;
  gemm_core(A1, B1, K1P, tileM, tileN, As, Bs, acc);
  const int tid = threadIdx.x, lane = tid & 63, wid = tid >> 6;
  const int wr = wid >> 1, wc = wid & 1, quad = lane >> 4, m16 = lane & 15;
#pragma unroll
  for (int i = 0; i < 4; ++i) {
    const int row0 = tileM + wr * 64 + i * 16 + quad * 4;
#pragma unroll
    for (int j = 0; j < 4; ++j) {
      const int col = tileN + wc * 64 + j * 16 + m16;
      const float bias = b1[col];
#pragma unroll
      for (int r = 0; r < 4; ++r) {
        const float v = acc[i][j][r] + bias;
        const int rr = row0 + r;
        if (col < 6144) {
          qkv[(size_t)rr * 6144 + col] = (bf16_t)v;
        } else if (col < 9216) {
          vt[(size_t)(col - 6144) * SEQ + rr] = (bf16_t)v;
        } else {
          A2[(size_t)rr * K2P + 3072 + (col - 9216)] = (bf16_t)gelu_tanh(v);
        }
      }
    }
  }
}

// GEMM2: A2(4608x15424) @ B2(3072x15424)^T + b2, out = x + gate*val (fp32)
__global__ __launch_bounds__(256, 2) void k_gemm2(const bf16_t* __restrict__ A2,
                                                  const bf16_t* __restrict__ B2,
                                                  const float* __restrict__ b2,
                                                  const float* __restrict__ x,
                                                  const float* __restrict__ mod,
                                                  float* __restrict__ out) {
  __shared__ __align__(16) bf16_t As[8192];
  __shared__ __align__(16) bf16_t Bs[8192];
  f32x4 acc[4][4];
  const int tileM = (blockIdx.x % 36) * 128, tileN = (blockIdx.x / 36) * 128;
  gemm_core(A2, B2, K2P, tileM, tileN, As, Bs, acc);
  const int tid = threadIdx.x, lane = tid & 63, wid = tid >> 6;
  const int wr = wid >> 1, wc = wid & 1, quad = lane >> 4, m16 = lane & 15;
#pragma unroll
  for (int i = 0; i < 4; ++i) {
    const int row0 = tileM + wr * 64 + i * 16 + quad * 4;
#pragma unroll
    for (int j = 0; j < 4; ++j) {
      const int col = tileN + wc * 64 + j * 16 + m16;
      const float bias = b2[col];
      const float gate = mod[2 * HIDC + col];
#pragma unroll
      for (int r = 0; r < 4; ++r) {
        const int rr = row0 + r;
        const float v = acc[i][j][r] + bias;
        out[(size_t)rr * HIDC + col] = x[(size_t)rr * HIDC + col] + gate * v;
      }
    }
  }
}

// ---------------------------------------------------------------------------
// RMSNorm + RoPE + repack: one wave per (token, head, q-or-k)
__global__ __launch_bounds__(256) void k_qkprep(const bf16_t* __restrict__ qkv,
                                                const float* __restrict__ pe,
                                                const float* __restrict__ rqw,
                                                const float* __restrict__ rkw,
                                                bf16_t* __restrict__ qp,
                                                bf16_t* __restrict__ kp) {
  const int lane = threadIdx.x & 63, wid = threadIdx.x >> 6;
  int g = blockIdx.x * 4 + wid;
  const int which = (g >= SEQ * NHEAD) ? 1 : 0;
  g -= which * SEQ * NHEAD;
  const int l = g / NHEAD, h = g % NHEAD;
  const int d0 = lane * 2;
  const bf16_t* src = qkv + (size_t)l * 6144 + which * HIDC + h * HDIM + d0;
  float x0 = (float)src[0], x1 = (float)src[1];
  float ss = x0 * x0 + x1 * x1;
#pragma unroll
  for (int o = 32; o; o >>= 1) ss += __shfl_xor(ss, o);
  const float rstd = rsqrtf(ss * (1.f / HDIM) + 1e-6f);
  const float* wv = which ? rkw : rqw;
  x0 *= rstd * wv[d0];
  x1 *= rstd * wv[d0 + 1];
  const float4 rr = *(const float4*)(pe + (size_t)l * 256 + lane * 4);  // r00 r01 r10 r11
  bf16x2 o2 = {(bf16_t)(rr.x * x0 + rr.y * x1), (bf16_t)(rr.z * x0 + rr.w * x1)};
  bf16_t* dst = (which ? kp : qp) + (size_t)(h * SEQ + l) * HDIM + d0;
  *(bf16x2*)dst = o2;
}

// ---------------------------------------------------------------------------
// Flash attention: block = (head, 64 q-rows), wave = 16 q-rows, K/V tiles of 64
__global__ __launch_bounds__(256, 2) void k_attn(const bf16_t* __restrict__ qp,
                                                 const bf16_t* __restrict__ kp,
                                                 const bf16_t* __restrict__ vt,
                                                 bf16_t* __restrict__ A2) {
  __shared__ __align__(16) bf16_t Ks[16 * 64 * 8];   // [dchunk16][key64][8]
  __shared__ __align__(16) bf16_t Vs[8 * 128 * 8];   // [kchunk8][d128][8]
  __shared__ __align__(16) bf16_t Ps[4][1024];       // per wave [kchunk8][row16][8]
  const float SM_SCALE = 0.08838834764831845f;       // 1/sqrt(128)
  const int tid = threadIdx.x, lane = tid & 63, wid = tid >> 6;
  const int quad = lane >> 4, m16 = lane & 15;
  const int h = blockIdx.x / 72, qt = blockIdx.x % 72;
  const int qbase = qt * 64 + wid * 16;
  bf16x8 qf[4];
  {
    const bf16_t* qr = qp + (size_t)(h * SEQ + qbase + m16) * HDIM + quad * 8;
#pragma unroll
    for (int c = 0; c < 4; ++c) qf[c] = *(const bf16x8*)(qr + c * 32);
  }
  const f32x4 fzero = {0.f, 0.f, 0.f, 0.f};
  f32x4 oacc[8];
#pragma unroll
  for (int j2 = 0; j2 < 8; ++j2) oacc[j2] = fzero;
  float mrun[4] = {-1e30f, -1e30f, -1e30f, -1e30f};
  float lrun[4] = {0.f, 0.f, 0.f, 0.f};
  const bf16_t* kg = kp + (size_t)h * SEQ * HDIM;
  const bf16_t* vg = vt + (size_t)h * HDIM * SEQ;
  for (int kt = 0; kt < SEQ; kt += 64) {
    __syncthreads();
#pragma unroll
    for (int s = 0; s < 4; ++s) {
      int o = s * 256 + tid;
      gl_lds16(kg + (size_t)(kt + (o & 63)) * HDIM + (o >> 6) * 8, Ks + (size_t)o * 8);
    }
#pragma unroll
    for (int s = 0; s < 4; ++s) {
      int o = s * 256 + tid;
      gl_lds16(vg + (size_t)(o & 127) * SEQ + kt + (o >> 7) * 8, Vs + (size_t)o * 8);
    }
    __syncthreads();
    f32x4 st[4];
#pragma unroll
    for (int jj = 0; jj < 4; ++jj) st[jj] = fzero;
#pragma unroll
    for (int c = 0; c < 4; ++c)
#pragma unroll
      for (int jj = 0; jj < 4; ++jj) {
        bf16x8 kf = *(const bf16x8*)(Ks + (size_t)((c * 4 + quad) * 64 + jj * 16 + m16) * 8);
        st[jj] = __builtin_amdgcn_mfma_f32_16x16x32_bf16(qf[c], kf, st[jj], 0, 0, 0);
      }
    float mnew[4], alpha[4], rsum[4];
#pragma unroll
    for (int r = 0; r < 4; ++r) {
      float mx = fmaxf(fmaxf(st[0][r], st[1][r]), fmaxf(st[2][r], st[3][r]));
#pragma unroll
      for (int o = 1; o < 16; o <<= 1) mx = fmaxf(mx, __shfl_xor(mx, o));
      mx *= SM_SCALE;
      float mn = fmaxf(mrun[r], mx);
      alpha[r] = __expf(mrun[r] - mn);
      mnew[r] = mn;
      mrun[r] = mn;
      rsum[r] = 0.f;
    }
#pragma unroll
    for (int jj = 0; jj < 4; ++jj) {
#pragma unroll
      for (int r = 0; r < 4; ++r) {
        float p = __expf(st[jj][r] * SM_SCALE - mnew[r]);
        rsum[r] += p;
        Ps[wid][(size_t)((jj * 2 + (m16 >> 3)) * 16 + quad * 4 + r) * 8 + (m16 & 7)] = (bf16_t)p;
      }
    }
#pragma unroll
    for (int r = 0; r < 4; ++r) {
      float t = rsum[r];
#pragma unroll
      for (int o = 1; o < 16; o <<= 1) t += __shfl_xor(t, o);
      lrun[r] = lrun[r] * alpha[r] + t;
    }
#pragma unroll
    for (int j2 = 0; j2 < 8; ++j2)
#pragma unroll
      for (int r = 0; r < 4; ++r) oacc[j2][r] *= alpha[r];
#pragma unroll
    for (int kc2 = 0; kc2 < 2; ++kc2) {
      bf16x8 pf = *(const bf16x8*)(&Ps[wid][(size_t)((kc2 * 4 + quad) * 16 + m16) * 8]);
#pragma unroll
      for (int j2 = 0; j2 < 8; ++j2) {
        bf16x8 vf = *(const bf16x8*)(Vs + (size_t)((kc2 * 4 + quad) * 128 + j2 * 16 + m16) * 8);
        oacc[j2] = __builtin_amdgcn_mfma_f32_16x16x32_bf16(pf, vf, oacc[j2], 0, 0, 0);
      }
    }
  }
#pragma unroll
  for (int j2 = 0; j2 < 8; ++j2) {
#pragma unroll
    for (int r = 0; r < 4; ++r) {
      const int row = qbase + quad * 4 + r;
      const int col = h * HDIM + j2 * 16 + m16;
      A2[(size_t)row * K2P + col] = (bf16_t)(oacc[j2][r] / lrun[r]);
    }
  }
}

// ---------------------------------------------------------------------------
extern "C" void kernel_launch(void* const* d_in, const int* in_sizes, int n_in,
                              void* d_out, int out_size, void* d_ws, size_t ws_size,
                              hipStream_t stream) {
  const float* x = (const float*)d_in[0];
  const float* vec = (const float*)d_in[1];
  const float* pe = (const float*)d_in[2];
  const float* mod_w = (const float*)d_in[3];
  const float* mod_b = (const float*)d_in[4];
  const float* w1 = (const float*)d_in[5];
  const float* b1 = (const float*)d_in[6];
  const float* ld1 = (const float*)d_in[7];
  const float* lu1 = (const float*)d_in[8];
  const float* w2 = (const float*)d_in[9];
  const float* b2 = (const float*)d_in[10];
  const float* ld2 = (const float*)d_in[11];
  const float* lu2 = (const float*)d_in[12];
  const float* rqw = (const float*)d_in[13];
  const float* rkw = (const float*)d_in[14];
  float* out = (float*)d_out;
  char* ws = (char*)d_ws;

  const size_t OFF_A1 = 36864;
  const size_t OFF_B = OFF_A1 + (size_t)SEQ * K1P * 2;
  const size_t OFF_QKV = OFF_B + (size_t)D1 * K1P * 2;
  const size_t OFF_QP = OFF_QKV + (size_t)SEQ * 6144 * 2;
  const size_t OFF_KP = OFF_QP + (size_t)NHEAD * SEQ * HDIM * 2;
  const size_t OFF_VT = OFF_KP + (size_t)NHEAD * SEQ * HDIM * 2;
  const size_t OFF_A2 = OFF_VT + (size_t)NHEAD * SEQ * HDIM * 2;

  float* mod = (float*)ws;
  bf16_t* A1 = (bf16_t*)(ws + OFF_A1);
  bf16_t* Bw = (bf16_t*)(ws + OFF_B);
  bf16_t* qkv = (bf16_t*)(ws + OFF_QKV);
  bf16_t* qp = (bf16_t*)(ws + OFF_QP);
  bf16_t* kp = (bf16_t*)(ws + OFF_KP);
  bf16_t* vt = (bf16_t*)(ws + OFF_VT);
  bf16_t* A2 = (bf16_t*)(ws + OFF_A2);

  k_mod<<<9216 / 4, 256, 0, stream>>>(vec, mod_w, mod_b, mod);
  k_ln<<<SEQ, 256, 0, stream>>>(x, mod, A1);
  k_lowrank<<<SEQ / 8, 256, 0, stream>>>(A1, ld1, A1, HIDC, K1P);
  k_convB<<<D1, 256, 0, stream>>>(w1, lu1, Bw, HIDC, K1P);
  k_gemm1<<<36 * 168, 256, 0, stream>>>(A1, Bw, b1, qkv, vt, A2);
  k_qkprep<<<SEQ * NHEAD * 2 / 4, 256, 0, stream>>>(qkv, pe, rqw, rkw, qp, kp);
  k_attn<<<NHEAD * 72, 256, 0, stream>>>(qp, kp, vt, A2);
  k_convB<<<HIDC, 256, 0, stream>>>(w2, lu2, Bw, K2DIM, K2P);
  k_lowrank<<<SEQ / 8, 256, 0, stream>>>(A2, ld2, A2, K2DIM, K2P);
  k_gemm2<<<36 * 24, 256, 0, stream>>>(A2, Bw, b2, x, mod, out);
}

// Round 2
// 5255.139 us; speedup vs baseline: 1.0224x; 1.0224x over previous
//
#include <hip/hip_runtime.h>
#include <cstdint>
#include <cstddef>

// ---------------------------------------------------------------------------
// FluxSingleStreamBlock on MI355X (gfx950), bf16 MFMA pipeline. Round 2:
//  - GEMM tiles 256(M)x128(N), BK=64, 256 thr, acc[4][8] (halves B re-reads,
//    2x MFMA per barrier interval vs 128x128)
//  - non-temporal epilogue stores (stop write-stream LLC eviction -> cut the
//    12.5x HBM over-fetch seen in R1: FETCH 2.06 GB vs 164 MB ideal)
//  - v written row-major (vraw, overlaid on qp/kp region) + separate LDS
//    transpose kernel instead of 2B scatter stores in the gemm1 epilogue
// ws layout (bytes):
//   [0,36864)                 mod (9216 f32): shift|scale|gate
//   A1  : 4608 x 3136 bf16    [x_mod | t1 | 0]
//   Bw  : 21504 x 3136 bf16   [w1 | lu1 | 0] (later overlaid by [w2|lu2|0])
//   qkv : 4608 x 6144 bf16    raw q,k from GEMM1
//   qp  : 24 x 4608 x 128 bf16  (vraw 4608x3072 overlays qp/kp until qkprep)
//   kp  : 24 x 4608 x 128 bf16
//   vt  : 3072 x 4608 bf16    v transposed [h*128+d][l]
//   A2  : 4608 x 15424 bf16   [attn | gelu(mlp) | t2 | 0]
// ---------------------------------------------------------------------------

#define HIDC 3072
#define NHEAD 24
#define HDIM 128
#define SEQ 4608
#define D1 21504     // 3*HID + MLP
#define K1P 3136     // 3072 + 64 pad (t1/lu1 + zeros)
#define K2DIM 15360  // HID + MLP
#define K2P 15424    // + 64 pad (t2/lu2 + zeros)

typedef __bf16 bf16_t;
typedef __bf16 bf16x2 __attribute__((ext_vector_type(2)));
typedef __bf16 bf16x4 __attribute__((ext_vector_type(4)));
typedef __bf16 bf16x8 __attribute__((ext_vector_type(8)));
typedef float f32x4 __attribute__((ext_vector_type(4)));

__device__ __forceinline__ void gl_lds16(const bf16_t* g, bf16_t* l) {
  __builtin_amdgcn_global_load_lds((__attribute__((address_space(1))) void*)(g),
                                   (__attribute__((address_space(3))) void*)(l),
                                   16, 0, 0);
}

__device__ __forceinline__ void nt_store_bf16(bf16_t* p, bf16_t v) {
  __builtin_nontemporal_store(v, p);
}

__device__ __forceinline__ float gelu_tanh(float v) {
  float c = v + 0.044715f * v * v * v;
  return 0.5f * v * (1.f + tanhf(0.7978845608028654f * c));
}

// ---------------------------------------------------------------------------
// mod = silu(vec) @ mod_w^T + mod_b   (9216 outputs, one wave each)
__global__ __launch_bounds__(256) void k_mod(const float* __restrict__ vec,
                                             const float* __restrict__ mw,
                                             const float* __restrict__ mb,
                                             float* __restrict__ mod) {
  const int lane = threadIdx.x & 63, wid = threadIdx.x >> 6;
  const int j = blockIdx.x * 4 + wid;
  const float* wr = mw + (size_t)j * HIDC;
  float s = 0.f;
  for (int i = lane * 4; i < HIDC; i += 256) {
    float4 w4 = *(const float4*)(wr + i);
    float4 v4 = *(const float4*)(vec + i);
    float a0 = v4.x / (1.f + __expf(-v4.x));
    float a1 = v4.y / (1.f + __expf(-v4.y));
    float a2 = v4.z / (1.f + __expf(-v4.z));
    float a3 = v4.w / (1.f + __expf(-v4.w));
    s += a0 * w4.x + a1 * w4.y + a2 * w4.z + a3 * w4.w;
  }
#pragma unroll
  for (int o = 32; o; o >>= 1) s += __shfl_down(s, o);
  if (lane == 0) mod[j] = s + mb[j];
}

// ---------------------------------------------------------------------------
// LayerNorm + modulation -> A1 (bf16), one block per token row
__global__ __launch_bounds__(256) void k_ln(const float* __restrict__ x,
                                            const float* __restrict__ mod,
                                            bf16_t* __restrict__ A1) {
  const int row = blockIdx.x;
  const int tid = threadIdx.x;
  const float* xr = x + (size_t)row * HIDC;
  float4 v[3];
  float s = 0.f, s2 = 0.f;
#pragma unroll
  for (int it = 0; it < 3; ++it) {
    v[it] = *(const float4*)(xr + (tid + 256 * it) * 4);
    s += v[it].x + v[it].y + v[it].z + v[it].w;
    s2 += v[it].x * v[it].x + v[it].y * v[it].y + v[it].z * v[it].z + v[it].w * v[it].w;
  }
  __shared__ float rbuf[8];
#pragma unroll
  for (int o = 32; o; o >>= 1) { s += __shfl_down(s, o); s2 += __shfl_down(s2, o); }
  const int lane = tid & 63, wid = tid >> 6;
  if (lane == 0) { rbuf[wid] = s; rbuf[4 + wid] = s2; }
  __syncthreads();
  s = rbuf[0] + rbuf[1] + rbuf[2] + rbuf[3];
  s2 = rbuf[4] + rbuf[5] + rbuf[6] + rbuf[7];
  const float mean = s * (1.f / HIDC);
  const float var = s2 * (1.f / HIDC) - mean * mean;
  const float rstd = rsqrtf(var + 1e-6f);
  bf16_t* arow = A1 + (size_t)row * K1P;
#pragma unroll
  for (int it = 0; it < 3; ++it) {
    const int c = (tid + 256 * it) * 4;
    float4 sc = *(const float4*)(mod + HIDC + c);  // scale
    float4 sh = *(const float4*)(mod + c);         // shift
    float y0 = ((v[it].x - mean) * rstd) * (1.f + sc.x) + sh.x;
    float y1 = ((v[it].y - mean) * rstd) * (1.f + sc.y) + sh.y;
    float y2 = ((v[it].z - mean) * rstd) * (1.f + sc.z) + sh.z;
    float y3 = ((v[it].w - mean) * rstd) * (1.f + sc.w) + sh.w;
    bf16x4 o = {(bf16_t)y0, (bf16_t)y1, (bf16_t)y2, (bf16_t)y3};
    *(bf16x4*)(arow + c) = o;
  }
}

// ---------------------------------------------------------------------------
// low-rank projection into A pad columns: A[row, Kmain+r] = sum_c A[row,c]*ld[r,c]
__global__ __launch_bounds__(256) void k_lowrank(const bf16_t* __restrict__ Abuf,
                                                 const float* __restrict__ ld,
                                                 bf16_t* __restrict__ Awr,
                                                 int Kmain, int Kpad) {
  const int r = threadIdx.x & 31, slot = threadIdx.x >> 5;
  const int row = blockIdx.x * 8 + slot;
  const bf16_t* a = Abuf + (size_t)row * Kpad;
  const float* lr = ld + (size_t)r * Kmain;
  float s = 0.f;
  for (int c = 0; c < Kmain; c += 8) {
    bf16x8 av = *(const bf16x8*)(a + c);
    float4 l0 = *(const float4*)(lr + c);
    float4 l1 = *(const float4*)(lr + c + 4);
    s += (float)av[0] * l0.x + (float)av[1] * l0.y + (float)av[2] * l0.z + (float)av[3] * l0.w;
    s += (float)av[4] * l1.x + (float)av[5] * l1.y + (float)av[6] * l1.z + (float)av[7] * l1.w;
  }
  bf16_t* w = Awr + (size_t)row * Kpad + Kmain;
  w[r] = (bf16_t)s;
  w[32 + r] = (bf16_t)0.f;
}

// ---------------------------------------------------------------------------
// Pack [w | lu | 0] row to bf16 (cached stores: Bw is re-read many times)
__global__ __launch_bounds__(256) void k_convB(const float* __restrict__ w,
                                               const float* __restrict__ lu,
                                               bf16_t* __restrict__ B,
                                               int Kmain, int Kpad) {
  const int row = blockIdx.x;
  const float* wr = w + (size_t)row * Kmain;
  const float* lr = lu + (size_t)row * 32;
  bf16_t* br = B + (size_t)row * Kpad;
  for (int c = threadIdx.x * 4; c < Kpad; c += 1024) {
    float4 v;
    if (c < Kmain) v = *(const float4*)(wr + c);
    else if (c < Kmain + 32) v = *(const float4*)(lr + (c - Kmain));
    else v = make_float4(0.f, 0.f, 0.f, 0.f);
    bf16x4 o = {(bf16_t)v.x, (bf16_t)v.y, (bf16_t)v.z, (bf16_t)v.w};
    *(bf16x4*)(br + c) = o;
  }
}

// ---------------------------------------------------------------------------
// 256x128 tile GEMM core, C = A @ B^T. A:(M x K), B:(N x K) row-major.
// 4 waves; wave w owns rows [w*64, w*64+64) x all 128 cols. acc[4][8].
// LDS [kchunk(8)][row][8 bf16], As 32KB + Bs 16KB.
__device__ __forceinline__ void gemm_core(const bf16_t* __restrict__ A,
                                          const bf16_t* __restrict__ B,
                                          const int K, const int tileM, const int tileN,
                                          bf16_t* As, bf16_t* Bs, f32x4 acc[4][8]) {
  const int tid = threadIdx.x, lane = tid & 63, w = tid >> 6;
  const int quad = lane >> 4, m16 = lane & 15;
  const f32x4 fzero = {0.f, 0.f, 0.f, 0.f};
#pragma unroll
  for (int i = 0; i < 4; ++i)
#pragma unroll
    for (int j = 0; j < 8; ++j) acc[i][j] = fzero;
  const bf16_t* Ag = A + (size_t)tileM * K;
  const bf16_t* Bg = B + (size_t)tileN * K;
  for (int kt = 0; kt < K; kt += 64) {
    __syncthreads();
#pragma unroll
    for (int s = 0; s < 8; ++s) {
      int o = s * 256 + tid;
      gl_lds16(Ag + (size_t)(o & 255) * K + (size_t)(kt + (o >> 8) * 8), As + (size_t)o * 8);
    }
#pragma unroll
    for (int s = 0; s < 4; ++s) {
      int o = s * 256 + tid;
      gl_lds16(Bg + (size_t)(o & 127) * K + (size_t)(kt + (o >> 7) * 8), Bs + (size_t)o * 8);
    }
    __syncthreads();
#pragma unroll
    for (int kk = 0; kk < 2; ++kk) {
      bf16x8 af[4], bfr[8];
#pragma unroll
      for (int i = 0; i < 4; ++i)
        af[i] = *(const bf16x8*)(As + (size_t)((kk * 4 + quad) * 256 + w * 64 + i * 16 + m16) * 8);
#pragma unroll
      for (int j = 0; j < 8; ++j)
        bfr[j] = *(const bf16x8*)(Bs + (size_t)((kk * 4 + quad) * 128 + j * 16 + m16) * 8);
#pragma unroll
      for (int i = 0; i < 4; ++i)
#pragma unroll
        for (int j = 0; j < 8; ++j)
          acc[i][j] = __builtin_amdgcn_mfma_f32_16x16x32_bf16(af[i], bfr[j], acc[i][j], 0, 0, 0);
    }
  }
}

// GEMM1: A1(4608x3136) @ B1(21504x3136)^T + b1. tileN is 128-aligned so the
// epilogue region (qk / v / mlp) is block-uniform.
__global__ __launch_bounds__(256, 2) void k_gemm1(const bf16_t* __restrict__ A1,
                                                  const bf16_t* __restrict__ B1,
                                                  const float* __restrict__ b1,
                                                  bf16_t* __restrict__ qkv,
                                                  bf16_t* __restrict__ vraw,
                                                  bf16_t* __restrict__ A2) {
  __shared__ __align__(16) bf16_t As[16384];
  __shared__ __align__(16) bf16_t Bs[8192];
  f32x4 acc[4][8];
  const int tileM = (blockIdx.x % 18) * 256, tileN = (blockIdx.x / 18) * 128;
  gemm_core(A1, B1, K1P, tileM, tileN, As, Bs, acc);
  const int tid = threadIdx.x, lane = tid & 63, w = tid >> 6;
  const int quad = lane >> 4, m16 = lane & 15;
#pragma unroll
  for (int i = 0; i < 4; ++i) {
    const int row0 = tileM + w * 64 + i * 16 + quad * 4;
#pragma unroll
    for (int j = 0; j < 8; ++j) {
      const int col = tileN + j * 16 + m16;
      const float bias = b1[col];
#pragma unroll
      for (int r = 0; r < 4; ++r) {
        const float v = acc[i][j][r] + bias;
        const int rr = row0 + r;
        if (col < 6144) {
          nt_store_bf16(qkv + (size_t)rr * 6144 + col, (bf16_t)v);
        } else if (col < 9216) {
          nt_store_bf16(vraw + (size_t)rr * HIDC + (col - 6144), (bf16_t)v);
        } else {
          nt_store_bf16(A2 + (size_t)rr * K2P + HIDC + (col - 9216), (bf16_t)gelu_tanh(v));
        }
      }
    }
  }
}

// GEMM2: A2(4608x15424) @ B2(3072x15424)^T + b2, out = x + gate*val (fp32)
__global__ __launch_bounds__(256, 2) void k_gemm2(const bf16_t* __restrict__ A2,
                                                  const bf16_t* __restrict__ B2,
                                                  const float* __restrict__ b2,
                                                  const float* __restrict__ x,
                                                  const float* __restrict__ mod,
                                                  float* __restrict__ out) {
  __shared__ __align__(16) bf16_t As[16384];
  __shared__ __align__(16) bf16_t Bs[8192];
  f32x4 acc[4][8];
  const int tileM = (blockIdx.x % 18) * 256, tileN = (blockIdx.x / 18) * 128;
  gemm_core(A2, B2, K2P, tileM, tileN, As, Bs, acc);
  const int tid = threadIdx.x, lane = tid & 63, w = tid >> 6;
  const int quad = lane >> 4, m16 = lane & 15;
#pragma unroll
  for (int i = 0; i < 4; ++i) {
    const int row0 = tileM + w * 64 + i * 16 + quad * 4;
#pragma unroll
    for (int j = 0; j < 8; ++j) {
      const int col = tileN + j * 16 + m16;
      const float bias = b2[col];
      const float gate = mod[2 * HIDC + col];
#pragma unroll
      for (int r = 0; r < 4; ++r) {
        const int rr = row0 + r;
        const float v = acc[i][j][r] + bias;
        __builtin_nontemporal_store(x[(size_t)rr * HIDC + col] + gate * v,
                                    out + (size_t)rr * HIDC + col);
      }
    }
  }
}

// ---------------------------------------------------------------------------
// v transpose: vraw (4608 x 3072, [l][h*128+d]) -> vt (3072 x 4608, [h*128+d][l])
__global__ __launch_bounds__(256) void k_vtrans(const bf16_t* __restrict__ vraw,
                                                bf16_t* __restrict__ vt) {
  __shared__ bf16_t Ts[64][68];
  const int tid = threadIdx.x;
  const int l0 = (blockIdx.x % 72) * 64, c0 = (blockIdx.x / 72) * 64;
#pragma unroll
  for (int s = 0; s < 2; ++s) {
    const int idx = s * 256 + tid;
    const int lrow = idx >> 3, c8 = (idx & 7) * 8;
    bf16x8 v = *(const bf16x8*)(vraw + (size_t)(l0 + lrow) * HIDC + c0 + c8);
#pragma unroll
    for (int e = 0; e < 8; ++e) Ts[c8 + e][lrow] = v[e];
  }
  __syncthreads();
#pragma unroll
  for (int s = 0; s < 2; ++s) {
    const int idx = s * 256 + tid;
    const int drow = idx >> 3, l8 = (idx & 7) * 8;
    bf16x8 v;
#pragma unroll
    for (int e = 0; e < 8; ++e) v[e] = Ts[drow][l8 + e];
    *(bf16x8*)(vt + (size_t)(c0 + drow) * SEQ + l0 + l8) = v;
  }
}

// ---------------------------------------------------------------------------
// RMSNorm + RoPE + repack: one wave per (token, head, q-or-k)
__global__ __launch_bounds__(256) void k_qkprep(const bf16_t* __restrict__ qkv,
                                                const float* __restrict__ pe,
                                                const float* __restrict__ rqw,
                                                const float* __restrict__ rkw,
                                                bf16_t* __restrict__ qp,
                                                bf16_t* __restrict__ kp) {
  const int lane = threadIdx.x & 63, wid = threadIdx.x >> 6;
  int g = blockIdx.x * 4 + wid;
  const int which = (g >= SEQ * NHEAD) ? 1 : 0;
  g -= which * SEQ * NHEAD;
  const int l = g / NHEAD, h = g % NHEAD;
  const int d0 = lane * 2;
  const bf16_t* src = qkv + (size_t)l * 6144 + which * HIDC + h * HDIM + d0;
  bf16x2 xv = *(const bf16x2*)src;
  float x0 = (float)xv[0], x1 = (float)xv[1];
  float ss = x0 * x0 + x1 * x1;
#pragma unroll
  for (int o = 32; o; o >>= 1) ss += __shfl_xor(ss, o);
  const float rstd = rsqrtf(ss * (1.f / HDIM) + 1e-6f);
  const float* wv = which ? rkw : rqw;
  x0 *= rstd * wv[d0];
  x1 *= rstd * wv[d0 + 1];
  const float4 rr = *(const float4*)(pe + (size_t)l * 256 + lane * 4);  // r00 r01 r10 r11
  bf16x2 o2 = {(bf16_t)(rr.x * x0 + rr.y * x1), (bf16_t)(rr.z * x0 + rr.w * x1)};
  bf16_t* dst = (which ? kp : qp) + (size_t)(h * SEQ + l) * HDIM + d0;
  *(bf16x2*)dst = o2;
}

// ---------------------------------------------------------------------------
// Flash attention: block = (head, 64 q-rows), wave = 16 q-rows, K/V tiles of 64
__global__ __launch_bounds__(256, 2) void k_attn(const bf16_t* __restrict__ qp,
                                                 const bf16_t* __restrict__ kp,
                                                 const bf16_t* __restrict__ vt,
                                                 bf16_t* __restrict__ A2) {
  __shared__ __align__(16) bf16_t Ks[16 * 64 * 8];   // [dchunk16][key64][8]
  __shared__ __align__(16) bf16_t Vs[8 * 128 * 8];   // [kchunk8][d128][8]
  __shared__ __align__(16) bf16_t Ps[4][1024];       // per wave [kchunk8][row16][8]
  const float SM_SCALE = 0.08838834764831845f;       // 1/sqrt(128)
  const int tid = threadIdx.x, lane = tid & 63, wid = tid >> 6;
  const int quad = lane >> 4, m16 = lane & 15;
  const int h = blockIdx.x / 72, qt = blockIdx.x % 72;
  const int qbase = qt * 64 + wid * 16;
  bf16x8 qf[4];
  {
    const bf16_t* qr = qp + (size_t)(h * SEQ + qbase + m16) * HDIM + quad * 8;
#pragma unroll
    for (int c = 0; c < 4; ++c) qf[c] = *(const bf16x8*)(qr + c * 32);
  }
  const f32x4 fzero = {0.f, 0.f, 0.f, 0.f};
  f32x4 oacc[8];
#pragma unroll
  for (int j2 = 0; j2 < 8; ++j2) oacc[j2] = fzero;
  float mrun[4] = {-1e30f, -1e30f, -1e30f, -1e30f};
  float lrun[4] = {0.f, 0.f, 0.f, 0.f};
  const bf16_t* kg = kp + (size_t)h * SEQ * HDIM;
  const bf16_t* vg = vt + (size_t)h * HDIM * SEQ;
  for (int kt = 0; kt < SEQ; kt += 64) {
    __syncthreads();
#pragma unroll
    for (int s = 0; s < 4; ++s) {
      int o = s * 256 + tid;
      gl_lds16(kg + (size_t)(kt + (o & 63)) * HDIM + (o >> 6) * 8, Ks + (size_t)o * 8);
    }
#pragma unroll
    for (int s = 0; s < 4; ++s) {
      int o = s * 256 + tid;
      gl_lds16(vg + (size_t)(o & 127) * SEQ + kt + (o >> 7) * 8, Vs + (size_t)o * 8);
    }
    __syncthreads();
    f32x4 st[4];
#pragma unroll
    for (int jj = 0; jj < 4; ++jj) st[jj] = fzero;
#pragma unroll
    for (int c = 0; c < 4; ++c)
#pragma unroll
      for (int jj = 0; jj < 4; ++jj) {
        bf16x8 kf = *(const bf16x8*)(Ks + (size_t)((c * 4 + quad) * 64 + jj * 16 + m16) * 8);
        st[jj] = __builtin_amdgcn_mfma_f32_16x16x32_bf16(qf[c], kf, st[jj], 0, 0, 0);
      }
    float mnew[4], alpha[4], rsum[4];
#pragma unroll
    for (int r = 0; r < 4; ++r) {
      float mx = fmaxf(fmaxf(st[0][r], st[1][r]), fmaxf(st[2][r], st[3][r]));
#pragma unroll
      for (int o = 1; o < 16; o <<= 1) mx = fmaxf(mx, __shfl_xor(mx, o));
      mx *= SM_SCALE;
      float mn = fmaxf(mrun[r], mx);
      alpha[r] = __expf(mrun[r] - mn);
      mnew[r] = mn;
      mrun[r] = mn;
      rsum[r] = 0.f;
    }
#pragma unroll
    for (int jj = 0; jj < 4; ++jj) {
#pragma unroll
      for (int r = 0; r < 4; ++r) {
        float p = __expf(st[jj][r] * SM_SCALE - mnew[r]);
        rsum[r] += p;
        Ps[wid][(size_t)((jj * 2 + (m16 >> 3)) * 16 + quad * 4 + r) * 8 + (m16 & 7)] = (bf16_t)p;
      }
    }
#pragma unroll
    for (int r = 0; r < 4; ++r) {
      float t = rsum[r];
#pragma unroll
      for (int o = 1; o < 16; o <<= 1) t += __shfl_xor(t, o);
      lrun[r] = lrun[r] * alpha[r] + t;
    }
#pragma unroll
    for (int j2 = 0; j2 < 8; ++j2)
#pragma unroll
      for (int r = 0; r < 4; ++r) oacc[j2][r] *= alpha[r];
#pragma unroll
    for (int kc2 = 0; kc2 < 2; ++kc2) {
      bf16x8 pf = *(const bf16x8*)(&Ps[wid][(size_t)((kc2 * 4 + quad) * 16 + m16) * 8]);
#pragma unroll
      for (int j2 = 0; j2 < 8; ++j2) {
        bf16x8 vf = *(const bf16x8*)(Vs + (size_t)((kc2 * 4 + quad) * 128 + j2 * 16 + m16) * 8);
        oacc[j2] = __builtin_amdgcn_mfma_f32_16x16x32_bf16(pf, vf, oacc[j2], 0, 0, 0);
      }
    }
  }
#pragma unroll
  for (int j2 = 0; j2 < 8; ++j2) {
#pragma unroll
    for (int r = 0; r < 4; ++r) {
      const int row = qbase + quad * 4 + r;
      const int col = h * HDIM + j2 * 16 + m16;
      nt_store_bf16(A2 + (size_t)row * K2P + col, (bf16_t)(oacc[j2][r] / lrun[r]));
    }
  }
}

// ---------------------------------------------------------------------------
extern "C" void kernel_launch(void* const* d_in, const int* in_sizes, int n_in,
                              void* d_out, int out_size, void* d_ws, size_t ws_size,
                              hipStream_t stream) {
  const float* x = (const float*)d_in[0];
  const float* vec = (const float*)d_in[1];
  const float* pe = (const float*)d_in[2];
  const float* mod_w = (const float*)d_in[3];
  const float* mod_b = (const float*)d_in[4];
  const float* w1 = (const float*)d_in[5];
  const float* b1 = (const float*)d_in[6];
  const float* ld1 = (const float*)d_in[7];
  const float* lu1 = (const float*)d_in[8];
  const float* w2 = (const float*)d_in[9];
  const float* b2 = (const float*)d_in[10];
  const float* ld2 = (const float*)d_in[11];
  const float* lu2 = (const float*)d_in[12];
  const float* rqw = (const float*)d_in[13];
  const float* rkw = (const float*)d_in[14];
  float* out = (float*)d_out;
  char* ws = (char*)d_ws;

  const size_t OFF_A1 = 36864;
  const size_t OFF_B = OFF_A1 + (size_t)SEQ * K1P * 2;
  const size_t OFF_QKV = OFF_B + (size_t)D1 * K1P * 2;
  const size_t OFF_QP = OFF_QKV + (size_t)SEQ * 6144 * 2;
  const size_t OFF_KP = OFF_QP + (size_t)NHEAD * SEQ * HDIM * 2;
  const size_t OFF_VT = OFF_KP + (size_t)NHEAD * SEQ * HDIM * 2;
  const size_t OFF_A2 = OFF_VT + (size_t)NHEAD * SEQ * HDIM * 2;

  float* mod = (float*)ws;
  bf16_t* A1 = (bf16_t*)(ws + OFF_A1);
  bf16_t* Bw = (bf16_t*)(ws + OFF_B);
  bf16_t* qkv = (bf16_t*)(ws + OFF_QKV);
  bf16_t* qp = (bf16_t*)(ws + OFF_QP);
  bf16_t* vraw = (bf16_t*)(ws + OFF_QP);  // overlays qp/kp until k_qkprep runs
  bf16_t* kp = (bf16_t*)(ws + OFF_KP);
  bf16_t* vt = (bf16_t*)(ws + OFF_VT);
  bf16_t* A2 = (bf16_t*)(ws + OFF_A2);

  k_convB<<<D1, 256, 0, stream>>>(w1, lu1, Bw, HIDC, K1P);
  k_mod<<<9216 / 4, 256, 0, stream>>>(vec, mod_w, mod_b, mod);
  k_ln<<<SEQ, 256, 0, stream>>>(x, mod, A1);
  k_lowrank<<<SEQ / 8, 256, 0, stream>>>(A1, ld1, A1, HIDC, K1P);
  k_gemm1<<<18 * 168, 256, 0, stream>>>(A1, Bw, b1, qkv, vraw, A2);
  k_vtrans<<<72 * 48, 256, 0, stream>>>(vraw, vt);
  k_qkprep<<<SEQ * NHEAD * 2 / 4, 256, 0, stream>>>(qkv, pe, rqw, rkw, qp, kp);
  k_attn<<<NHEAD * 72, 256, 0, stream>>>(qp, kp, vt, A2);
  k_convB<<<HIDC, 256, 0, stream>>>(w2, lu2, Bw, K2DIM, K2P);
  k_lowrank<<<SEQ / 8, 256, 0, stream>>>(A2, ld2, A2, K2DIM, K2P);
  k_gemm2<<<18 * 24, 256, 0, stream>>>(A2, Bw, b2, x, mod, out);
}